// Round 7
// baseline (203.279 us; speedup 1.0000x reference)
//
#include <hip/hip_runtime.h>
#include <stdint.h>

// TimeVaryingDelayLine forward — LDS multi-pass gather, v5.
//
// v4 (R6) failed: overlap-by-1 pass stride (16383 floats) made staging
// addresses g ≡ -p (mod 4); 16B loads in the buffer region then straddled the
// per-series buffer end (read next series' data) and were only 4B-aligned.
// v5 uses overlap-by-4 (stride 16380 floats = 65520B, 16B-multiple):
//  - g always ≡ 0 mod 4 -> buffer-region loads cap at bs[39996..39999],
//    never past the series buffer; 16B-aligned global_load_lds sources.
//  - membership: ub = b1 - p*65520 in [0, 65516] (multiples of 4 tile the
//    b1 axis exactly once); tap0 at ub+4 <= 65520 < 65536 stays in-window.
//  - branchless scan: sub + clamp + always-issued ds_read2 + lerp + cndmask.
//  - CHUNK=16384, 512 threads, 32 elems/thread, NPASS=4, dbuf 2x64KB,
//    stage-ahead, one barrier per pass.

#define MAX_DELAY 40000
#define T_LEN     1000000
#define XPAD      (MAX_DELAY + T_LEN)   // 1,040,000 floats per series
#define CHUNK     16384                 // output elems per block
#define S_ELEMS   16384                 // floats per stage buffer
#define S_BYTES   65536
#define STRIDE_E  (S_ELEMS - 4)         // 16380 floats between pass windows
#define STRIDE_B  (STRIDE_E * 4)        // 65520 bytes
#define VALID_MAX (STRIDE_B - 4)        // membership: ub <= 65516
#define NPASS     4                     // pass3 max ub = 225528-3*65520 = 28968
#define CPS       62                    // ceil(T_LEN/CHUNK)
#define NXCD      8

typedef __attribute__((address_space(3))) uint32_t       lds_u32;
typedef const __attribute__((address_space(1))) uint32_t glb_u32;

__global__ __launch_bounds__(512, 2) void tvdl_kernel(
    const float* __restrict__ x,
    const float* __restrict__ dt,
    const float* __restrict__ buf,
    float* __restrict__ y,
    int chunk_per_xcd)
{
    __shared__ float lds[2][S_ELEMS];

    int bid = blockIdx.x;
    int lb  = (bid & (NXCD - 1)) * chunk_per_xcd + (bid >> 3);  // XCD-contiguous
    int nc  = lb / CPS;                 // series 0..15
    int c   = lb - nc * CPS;            // chunk 0..61
    int t0  = c * CHUNK;
    int tid = threadIdx.x;

    const float* __restrict__ xs  = x   + (size_t)nc * T_LEN;
    const float* __restrict__ bs  = buf + (size_t)nc * MAX_DELAY;
    const float* __restrict__ dts = dt  + (size_t)nc * T_LEN;
    float*       __restrict__ ys  = y   + (size_t)nc * T_LEN;

    // ---- per-element setup: read dt once, keep (b1, frac, acc) in regs ----
    int   b1[8][4];     // byte offset of tap1 relative to window start t0
    float fr[8][4];
    float acc[8][4];

#pragma unroll
    for (int k = 0; k < 8; ++k) {
        int go   = (k * 512 + tid) * 4;
        int lidx = t0 + go;
        int lc   = lidx > T_LEN - 4 ? T_LEN - 4 : lidx;   // tail-chunk clamp
        float4 d4 = *reinterpret_cast<const float4*>(dts + lc);
        float dv[4] = {d4.x, d4.y, d4.z, d4.w};
#pragma unroll
        for (int j = 0; j < 4; ++j) {
            float dvj = dv[j];
            int   i0  = (int)dvj;                 // dt >= 0 -> trunc == floor
            fr[k][j]  = dvj - (float)i0;
            b1[k][j]  = (MAX_DELAY - 1 + (go + j) - i0) * 4;
            acc[k][j] = 0.0f;
        }
    }

    // ---- staging: pass p window = xpad floats [t0 + p*STRIDE_E, +16384) ----
#define STAGE(b, p)                                                          \
    {                                                                        \
        _Pragma("unroll")                                                    \
        for (int q = 0; q < 8; ++q) {                                        \
            int g = t0 + (p) * STRIDE_E + (q * 512 + tid) * 4;               \
            if (g > XPAD - 4) g = XPAD - 4;   /* tail clamp, mult-of-4 */    \
            const float* src = (g >= MAX_DELAY) ? (xs + (g - MAX_DELAY))     \
                                                : (bs + g);                  \
            float* dst = lds[b] + (size_t)(q * 512 + (tid & 448)) * 4;       \
            __builtin_amdgcn_global_load_lds((glb_u32*)src, (lds_u32*)dst,   \
                                             16, 0, 0);                      \
        }                                                                    \
    }

    STAGE(0, 0);
    __syncthreads();                    // vmcnt(0) drain -> lds[0] ready

#pragma unroll
    for (int p = 0; p < NPASS; ++p) {
        const int cur = p & 1;
        if (p + 1 < NPASS) STAGE(cur ^ 1, p + 1);   // async, lands by barrier

        const char* lb0 = (const char*)lds[cur];
#pragma unroll
        for (int k = 0; k < 8; ++k) {
#pragma unroll
            for (int j = 0; j < 4; ++j) {
                unsigned ub = (unsigned)(b1[k][j] - p * STRIDE_B);
                unsigned ad = ub < (unsigned)VALID_MAX ? ub : (unsigned)VALID_MAX;
                const float* lp = (const float*)(lb0 + ad);   // ds_read2_b32
                float t1v = lp[0];
                float t0v = lp[1];
                float r   = fmaf(fr[k][j], t1v - t0v, t0v);   // lerp
                acc[k][j] += (ub <= (unsigned)VALID_MAX) ? r : 0.0f;
            }
        }

        if (p + 1 < NPASS) __syncthreads();   // reads done + next stage landed
    }
#undef STAGE

    // ---- store ----
#pragma unroll
    for (int k = 0; k < 8; ++k) {
        int go = (k * 512 + tid) * 4;
        if (t0 + go < T_LEN) {
            *reinterpret_cast<float4*>(ys + t0 + go) =
                make_float4(acc[k][0], acc[k][1], acc[k][2], acc[k][3]);
        }
    }
}

extern "C" void kernel_launch(void* const* d_in, const int* in_sizes, int n_in,
                              void* d_out, int out_size, void* d_ws, size_t ws_size,
                              hipStream_t stream) {
    const float* x   = (const float*)d_in[0];
    const float* dt  = (const float*)d_in[1];
    const float* buf = (const float*)d_in[2];
    float* y = (float*)d_out;

    int nseries = out_size / T_LEN;                 // 16
    int blocks  = nseries * CPS;                    // 992 = 8 * 124
    int chunk_per_xcd = blocks / NXCD;              // 124
    tvdl_kernel<<<blocks, 512, 0, stream>>>(x, dt, buf, y, chunk_per_xcd);
}

// Round 8
// 202.599 us; speedup vs baseline: 1.0034x; 1.0034x over previous
//
#include <hip/hip_runtime.h>
#include <stdint.h>

// TimeVaryingDelayLine forward — LDS multi-pass gather, v6.
//
// v5 (R7) was correct but spilled ~340MB of scratch: __launch_bounds__(512,2)
// resolves to a 128-VGPR cap for 8-wave blocks, below the ~150-200 the state
// needs. v6 changes ONLY the bound to (512,1): VGPR cap 512; LDS (128KB)
// already limits residency to 1 block/CU = 2 waves/SIMD, which any <=256-reg
// allocation satisfies, so real occupancy is unchanged — only the reg cap.
//
// Structure (unchanged from v5):
//  - CHUNK=16384 outputs/block, 512 threads, 32 elems/thread.
//  - Window staged in NPASS=4 passes of 16384 floats, pass stride 16380
//    floats (overlap-by-4: 16B-aligned staging, no buffer-end straddle,
//    no tap-pair straddle).
//  - Branchless membership scan: sub + clamp + always-issued ds_read2 +
//    lerp + cndmask-add.
//  - Double buffer 2x64KB, stage-ahead via global_load_lds(16B), one
//    barrier per pass.

#define MAX_DELAY 40000
#define T_LEN     1000000
#define XPAD      (MAX_DELAY + T_LEN)   // 1,040,000 floats per series
#define CHUNK     16384                 // output elems per block
#define S_ELEMS   16384                 // floats per stage buffer
#define S_BYTES   65536
#define STRIDE_E  (S_ELEMS - 4)         // 16380 floats between pass windows
#define STRIDE_B  (STRIDE_E * 4)        // 65520 bytes
#define VALID_MAX (STRIDE_B - 4)        // membership: ub <= 65516
#define NPASS     4                     // pass3 max ub = 225528-3*65520 = 28968
#define CPS       62                    // ceil(T_LEN/CHUNK)
#define NXCD      8

typedef __attribute__((address_space(3))) uint32_t       lds_u32;
typedef const __attribute__((address_space(1))) uint32_t glb_u32;

__global__ __launch_bounds__(512, 1) void tvdl_kernel(
    const float* __restrict__ x,
    const float* __restrict__ dt,
    const float* __restrict__ buf,
    float* __restrict__ y,
    int chunk_per_xcd)
{
    __shared__ float lds[2][S_ELEMS];

    int bid = blockIdx.x;
    int lb  = (bid & (NXCD - 1)) * chunk_per_xcd + (bid >> 3);  // XCD-contiguous
    int nc  = lb / CPS;                 // series 0..15
    int c   = lb - nc * CPS;            // chunk 0..61
    int t0  = c * CHUNK;
    int tid = threadIdx.x;

    const float* __restrict__ xs  = x   + (size_t)nc * T_LEN;
    const float* __restrict__ bs  = buf + (size_t)nc * MAX_DELAY;
    const float* __restrict__ dts = dt  + (size_t)nc * T_LEN;
    float*       __restrict__ ys  = y   + (size_t)nc * T_LEN;

    // ---- per-element setup: read dt once, keep (b1, frac, acc) in regs ----
    int   b1[8][4];     // byte offset of tap1 relative to window start t0
    float fr[8][4];
    float acc[8][4];

#pragma unroll
    for (int k = 0; k < 8; ++k) {
        int go   = (k * 512 + tid) * 4;
        int lidx = t0 + go;
        int lc   = lidx > T_LEN - 4 ? T_LEN - 4 : lidx;   // tail-chunk clamp
        float4 d4 = *reinterpret_cast<const float4*>(dts + lc);
        float dv[4] = {d4.x, d4.y, d4.z, d4.w};
#pragma unroll
        for (int j = 0; j < 4; ++j) {
            float dvj = dv[j];
            int   i0  = (int)dvj;                 // dt >= 0 -> trunc == floor
            fr[k][j]  = dvj - (float)i0;
            b1[k][j]  = (MAX_DELAY - 1 + (go + j) - i0) * 4;
            acc[k][j] = 0.0f;
        }
    }

    // ---- staging: pass p window = xpad floats [t0 + p*STRIDE_E, +16384) ----
#define STAGE(b, p)                                                          \
    {                                                                        \
        _Pragma("unroll")                                                    \
        for (int q = 0; q < 8; ++q) {                                        \
            int g = t0 + (p) * STRIDE_E + (q * 512 + tid) * 4;               \
            if (g > XPAD - 4) g = XPAD - 4;   /* tail clamp, mult-of-4 */    \
            const float* src = (g >= MAX_DELAY) ? (xs + (g - MAX_DELAY))     \
                                                : (bs + g);                  \
            float* dst = lds[b] + (size_t)(q * 512 + (tid & 448)) * 4;       \
            __builtin_amdgcn_global_load_lds((glb_u32*)src, (lds_u32*)dst,   \
                                             16, 0, 0);                      \
        }                                                                    \
    }

    STAGE(0, 0);
    __syncthreads();                    // vmcnt(0) drain -> lds[0] ready

#pragma unroll
    for (int p = 0; p < NPASS; ++p) {
        const int cur = p & 1;
        if (p + 1 < NPASS) STAGE(cur ^ 1, p + 1);   // async, lands by barrier

        const char* lb0 = (const char*)lds[cur];
#pragma unroll
        for (int k = 0; k < 8; ++k) {
#pragma unroll
            for (int j = 0; j < 4; ++j) {
                unsigned ub = (unsigned)(b1[k][j] - p * STRIDE_B);
                unsigned ad = ub < (unsigned)VALID_MAX ? ub : (unsigned)VALID_MAX;
                const float* lp = (const float*)(lb0 + ad);   // ds_read2_b32
                float t1v = lp[0];
                float t0v = lp[1];
                float r   = fmaf(fr[k][j], t1v - t0v, t0v);   // lerp
                acc[k][j] += (ub <= (unsigned)VALID_MAX) ? r : 0.0f;
            }
        }

        if (p + 1 < NPASS) __syncthreads();   // reads done + next stage landed
    }
#undef STAGE

    // ---- store ----
#pragma unroll
    for (int k = 0; k < 8; ++k) {
        int go = (k * 512 + tid) * 4;
        if (t0 + go < T_LEN) {
            *reinterpret_cast<float4*>(ys + t0 + go) =
                make_float4(acc[k][0], acc[k][1], acc[k][2], acc[k][3]);
        }
    }
}

extern "C" void kernel_launch(void* const* d_in, const int* in_sizes, int n_in,
                              void* d_out, int out_size, void* d_ws, size_t ws_size,
                              hipStream_t stream) {
    const float* x   = (const float*)d_in[0];
    const float* dt  = (const float*)d_in[1];
    const float* buf = (const float*)d_in[2];
    float* y = (float*)d_out;

    int nseries = out_size / T_LEN;                 // 16
    int blocks  = nseries * CPS;                    // 992 = 8 * 124
    int chunk_per_xcd = blocks / NXCD;              // 124
    tvdl_kernel<<<blocks, 512, 0, stream>>>(x, dt, buf, y, chunk_per_xcd);
}